// Round 14
// baseline (1038.008 us; speedup 1.0000x reference)
//
#include <hip/hip_runtime.h>
#include <cstdint>
#include <cstddef>

#define TT 4
#define BB 8
#define CC 256
#define NN 1024
#define HEADS 8
#define DD 32

typedef __attribute__((ext_vector_type(4))) float f32x4;
typedef __attribute__((ext_vector_type(8))) short s16x8;
typedef unsigned short u16;
typedef unsigned int   u32;

__device__ __forceinline__ u16 bf16_rne(float x) {
    u32 u = __float_as_uint(x);
    return (u16)((u + 0x7FFFu + ((u >> 16) & 1u)) >> 16);
}
__device__ __forceinline__ float bf16f(u16 h) {
    return __uint_as_float(((u32)h) << 16);
}

// ---- prep: split f32 -> (hi,lo) bf16 planes, same layout (for weights) ----
__global__ __launch_bounds__(256) void prep_split(
    const float* __restrict__ src, u16* __restrict__ h, u16* __restrict__ l, int n4)
{
    for (int i = blockIdx.x * 256 + threadIdx.x; i < n4; i += gridDim.x * 256) {
        float4 v = reinterpret_cast<const float4*>(src)[i];
        ushort4 hh, ll;
        const float* vp = (const float*)&v;
#pragma unroll
        for (int e = 0; e < 4; ++e) {
            u16 hb = bf16_rne(vp[e]);
            ((u16*)&hh)[e] = hb;
            ((u16*)&ll)[e] = bf16_rne(vp[e] - bf16f(hb));
        }
        reinterpret_cast<ushort4*>(h)[i] = hh;
        reinterpret_cast<ushort4*>(l)[i] = ll;
    }
}

// ---- transpose+split: f32 [m][K][N] -> bf16 hi/lo [m][N][K] ----
template<int K, int N>
__global__ __launch_bounds__(256) void trans_split(
    const float* __restrict__ src, u16* __restrict__ dh, u16* __restrict__ dl)
{
    __shared__ float tile[64][65];
    const int tid = threadIdx.x;
    const int n0 = blockIdx.x * 64, k0 = blockIdx.y * 64, m = blockIdx.z;
    for (int i = tid; i < 4096; i += 256) {
        int kk = i >> 6, nn = i & 63;
        tile[kk][nn] = src[((size_t)m * K + k0 + kk) * N + n0 + nn];
    }
    __syncthreads();
    for (int i = tid; i < 4096; i += 256) {
        int nn = i >> 6, kk = i & 63;
        float f = tile[kk][nn];
        u16 hb = bf16_rne(f);
        const size_t a = ((size_t)m * N + n0 + nn) * K + k0 + kk;
        dh[a] = hb;
        dl[a] = bf16_rne(f - bf16f(hb));
    }
}

// ---- transpose bf16 [m][K][N] -> [m][N][K] ----
template<int K, int N>
__global__ __launch_bounds__(256) void trans_u16(
    const u16* __restrict__ src, u16* __restrict__ dst)
{
    __shared__ u16 tile[64][66];
    const int tid = threadIdx.x;
    const int n0 = blockIdx.x * 64, k0 = blockIdx.y * 64, m = blockIdx.z;
    for (int i = tid; i < 4096; i += 256) {
        int kk = i >> 6, nn = i & 63;
        tile[kk][nn] = src[((size_t)m * K + k0 + kk) * N + n0 + nn];
    }
    __syncthreads();
    for (int i = tid; i < 4096; i += 256) {
        int nn = i >> 6, kk = i & 63;
        dst[((size_t)m * N + n0 + nn) * K + k0 + kk] = tile[kk][nn];
    }
}

// ---- per-channel BN constants ----
__global__ __launch_bounds__(256) void prep_bn(
    const float* qbn, const float* kbn, const float* vbn, const float* pbn,
    const float* m1bn, const float* m2bn,
    const float* pb, const float* m1b, const float* m2b,
    float2* __restrict__ bnf, double* __restrict__ bnd)
{
    int c = blockIdx.x * 256 + threadIdx.x;
    if (c >= 2304) return;
    const float* bn; int ch, O; double bi = 0.0;
    if (c < 1024) {
        int s = c >> 8; ch = c & 255; O = 256;
        bn = s == 0 ? qbn : s == 1 ? kbn : s == 2 ? vbn : pbn;
        if (s == 3) bi = (double)pb[ch];
    } else if (c < 2048) { ch = c - 1024; O = 1024; bn = m1bn; bi = (double)m1b[ch]; }
    else                 { ch = c - 2048; O = 256;  bn = m2bn; bi = (double)m2b[ch]; }
    double g = (double)bn[0*O+ch], be = (double)bn[1*O+ch];
    double mu = (double)bn[2*O+ch], var = (double)bn[3*O+ch];
    double sd = g / sqrt(var + 1e-5);
    bnf[c] = make_float2((float)sd, (float)((bi - mu) * sd + be));
    bnd[c] = sd;
}

// ---- fused conv1x1 + BN + LIF: DIRECT-GLOBAL bf16-split MFMA ----
// No LDS for operands, no barriers in the GEMM: W rows [o][k] and transposed
// activations [n][k] are both k-contiguous, so every A/B fragment of
// mfma_f32_16x16x32_bf16 is one 16B coalesced global load (L1/L2-hot).
// Waves fully independent (wave = timestep t); TLP hides load latency.
// LDS only holds the f32 pre-activation exchange for the LIF epilogue.
// EPS screen + exact f64 recompute identical to rounds 12-13 (absmax 0.0).
// OUT_MODE: 0 = bf16 spikes [c][n] (qkv) | 1 = proj: f32 x_new [c][n] + bf16
// hi/lo planes TRANSPOSED [n][c] | 2 = bf16 spikes TRANSPOSED [n][o] (mlp1)
// | 3 = f32 + base [c][n] (mlp2). XE_BF16/XE_T describe recompute source.
template<bool SPLIT_IN, int CIN, int OUT_MODE, bool TRIPLE,
         bool XE_BF16, bool XE_T, int O>
__global__ __launch_bounds__(256, 3) void conv_kernel(
    const u16* __restrict__ XTH, const u16* __restrict__ XTL,
    const void* __restrict__ Xe_,
    const u16* __restrict__ WH0, const u16* __restrict__ WL0,
    const u16* __restrict__ WH1, const u16* __restrict__ WL1,
    const u16* __restrict__ WH2, const u16* __restrict__ WL2,
    const float* __restrict__ Wx0, const float* __restrict__ Wx1,
    const float* __restrict__ Wx2,
    const float* __restrict__ bnr0, const float* __restrict__ bnr1,
    const float* __restrict__ bnr2, const float* __restrict__ bias,
    const float2* __restrict__ bnf, const double* __restrict__ bnd,
    void* __restrict__ O0_, void* __restrict__ O1_, void* __restrict__ O2_,
    u16* __restrict__ OutH, u16* __restrict__ OutL,
    const float* __restrict__ base)
{
    constexpr float EPS = 3e-4f;
    __shared__ float pre[2 * 64 * 64];   // 32 KB epilogue exchange

    const int tid  = threadIdx.x;
    const int lane = tid & 63;
    const int wave = tid >> 6;          // == timestep t
    const int lr   = lane & 15;
    const int lk   = lane >> 4;
    const int n0 = blockIdx.x * 64;
    const int b  = blockIdx.z;

    int o0, cofs;
    const u16 *WH, *WL; const float *Wx, *bnr;
    void* Out_;
    if constexpr (TRIPLE) {
        const int sel = blockIdx.y >> 2;
        o0 = (blockIdx.y & 3) * 64;
        WH = sel==0?WH0:sel==1?WH1:WH2;  WL = sel==0?WL0:sel==1?WL1:WL2;
        Wx = sel==0?Wx0:sel==1?Wx1:Wx2;  bnr = sel==0?bnr0:sel==1?bnr1:bnr2;
        Out_ = sel==0?O0_:sel==1?O1_:O2_;
        cofs = sel * 256;
    } else {
        o0 = blockIdx.y * 64; WH = WH0; WL = WL0; Wx = Wx0; bnr = bnr0;
        Out_ = O0_; cofs = 0;
    }

    f32x4 acc[4][4];
#pragma unroll
    for (int mf = 0; mf < 4; ++mf)
#pragma unroll
        for (int nf = 0; nf < 4; ++nf)
            acc[mf][nf] = (f32x4){0.f, 0.f, 0.f, 0.f};

    // k-contiguous fragment row offsets (elements)
    u32 arow[4], brow[4];
#pragma unroll
    for (int mf = 0; mf < 4; ++mf)
        arow[mf] = (u32)((o0 + mf * 16 + lr) * CIN + lk * 8);
#pragma unroll
    for (int nf = 0; nf < 4; ++nf)
        brow[nf] = (u32)(((u32)(wave * BB + b) * NN + n0 + nf * 16 + lr) * CIN + lk * 8);

#pragma unroll 4
    for (int ks = 0; ks < CIN / 32; ++ks) {
        const u32 ko = ks * 32;
        s16x8 aH[4], aL[4], bH[4], bL[4];
#pragma unroll
        for (int mf = 0; mf < 4; ++mf) {
            aH[mf] = *(const s16x8*)&WH[(size_t)arow[mf] + ko];
            aL[mf] = *(const s16x8*)&WL[(size_t)arow[mf] + ko];
        }
#pragma unroll
        for (int nf = 0; nf < 4; ++nf) {
            bH[nf] = *(const s16x8*)&XTH[(size_t)brow[nf] + ko];
            if constexpr (SPLIT_IN)
                bL[nf] = *(const s16x8*)&XTL[(size_t)brow[nf] + ko];
        }
        __builtin_amdgcn_s_setprio(1);
#pragma unroll
        for (int mf = 0; mf < 4; ++mf)
#pragma unroll
            for (int nf = 0; nf < 4; ++nf) {
                acc[mf][nf] = __builtin_amdgcn_mfma_f32_16x16x32_bf16(
                    aH[mf], bH[nf], acc[mf][nf], 0, 0, 0);
                acc[mf][nf] = __builtin_amdgcn_mfma_f32_16x16x32_bf16(
                    aL[mf], bH[nf], acc[mf][nf], 0, 0, 0);
                if constexpr (SPLIT_IN)
                    acc[mf][nf] = __builtin_amdgcn_mfma_f32_16x16x32_bf16(
                        aH[mf], bL[nf], acc[mf][nf], 0, 0, 0);
            }
        __builtin_amdgcn_s_setprio(0);
    }

    // ---- epilogue ----
    const int nl = tid & 63;
    const int og = wave;

    auto dump = [&](int slot) {
#pragma unroll
        for (int mf = 0; mf < 4; ++mf)
#pragma unroll
            for (int nf = 0; nf < 4; ++nf)
#pragma unroll
                for (int r = 0; r < 4; ++r)
                    pre[(size_t)(slot * 64 + mf * 16 + lk * 4 + r) * 64
                        + nf * 16 + lr] = acc[mf][nf][r];
    };

    float2 sc[16];
#pragma unroll
    for (int i = 0; i < 16; ++i) sc[i] = bnf[cofs + o0 + og * 16 + i];

    u16   spb[2][16];   // OUT_MODE 2
    float xnb[2][16];   // OUT_MODE 1
    unsigned flags = 0;
    float vst[16];

    auto wrow_sp = [&](int t) {      // transposed bf16-spike row write (32B)
        const size_t a = ((size_t)(t * BB + b) * NN + n0 + nl) * O + o0 + og * 16;
        s16x8 v0, v1;
#pragma unroll
        for (int e = 0; e < 8; ++e) { v0[e] = (short)spb[t & 1][e]; v1[e] = (short)spb[t & 1][8 + e]; }
        *(s16x8*)&((u16*)Out_)[a] = v0;
        *(s16x8*)&((u16*)Out_)[a + 8] = v1;
    };
    auto wrow_xn = [&](int t) {      // transposed xn hi/lo row writes
        const size_t a = ((size_t)(t * BB + b) * NN + n0 + nl) * CC + o0 + og * 16;
        s16x8 h0, h1v, l0, l1v;
#pragma unroll
        for (int e = 0; e < 8; ++e) {
            u16 ha = bf16_rne(xnb[t & 1][e]);
            u16 hb = bf16_rne(xnb[t & 1][8 + e]);
            h0[e] = (short)ha; h1v[e] = (short)hb;
            l0[e] = (short)bf16_rne(xnb[t & 1][e] - bf16f(ha));
            l1v[e] = (short)bf16_rne(xnb[t & 1][8 + e] - bf16f(hb));
        }
        *(s16x8*)&OutH[a] = h0; *(s16x8*)&OutH[a + 8] = h1v;
        *(s16x8*)&OutL[a] = l0; *(s16x8*)&OutL[a + 8] = l1v;
    };

    auto do_round = [&](int tbase) {
#pragma unroll
        for (int i = 0; i < 16; ++i) {
            const int o = o0 + og * 16 + i;
            float v = (tbase == 0) ? 0.f : vst[i];
#pragma unroll
            for (int dt = 0; dt < 2; ++dt) {
                const int t = tbase + dt;
                float val = fmaf(pre[(size_t)(dt * 64 + og * 16 + i) * 64 + nl], sc[i].x, sc[i].y);
                v = v + (val - v) * 0.5f;
                if (fabsf(v - 1.0f) < EPS) flags |= (1u << i);
                float s = (v >= 1.0f) ? 1.f : 0.f;
                const size_t idx = (((size_t)t * BB + b) * O + o) * NN + n0 + nl;
                if constexpr (OUT_MODE == 0)
                    ((u16*)Out_)[idx] = (s > 0.5f) ? (u16)0x3F80 : (u16)0;
                else if constexpr (OUT_MODE == 1) {
                    float xn = base[idx] + s;
                    ((float*)Out_)[idx] = xn;
                    xnb[dt][i] = xn;
                } else if constexpr (OUT_MODE == 2)
                    spb[dt][i] = (s > 0.5f) ? (u16)0x3F80 : (u16)0;
                else ((float*)Out_)[idx] = base[idx] + s;
                v *= (1.f - s);
            }
            vst[i] = v;
        }
        if constexpr (OUT_MODE == 1) { wrow_xn(tbase); wrow_xn(tbase + 1); }
        if constexpr (OUT_MODE == 2) { wrow_sp(tbase); wrow_sp(tbase + 1); }
    };

    __syncthreads();
    if (wave < 2) dump(wave);
    __syncthreads();
    do_round(0);
    __syncthreads();
    if (wave >= 2) dump(wave - 2);
    __syncthreads();
    do_round(2);

    // ---- exact f64 recompute of flagged columns (rare) ----
    if (flags) {
#pragma unroll 1
        for (int i = 0; i < 16; ++i) {
            if (!(flags & (1u << i))) continue;
            const int o = o0 + og * 16 + i;
            const int n = n0 + nl;
            double s0 = 0.0, s1 = 0.0, s2 = 0.0, s3 = 0.0;
#pragma unroll 2
            for (int k = 0; k < CIN; ++k) {
                const double w = (double)Wx[(size_t)o * CIN + k];
                double xv[4];
#pragma unroll
                for (int t = 0; t < 4; ++t) {
                    size_t xi;
                    if constexpr (XE_T) xi = ((size_t)(t * BB + b) * NN + n) * CIN + k;
                    else                xi = ((size_t)(t * BB + b) * CIN + k) * NN + n;
                    if constexpr (XE_BF16) xv[t] = (double)bf16f(((const u16*)Xe_)[xi]);
                    else                   xv[t] = (double)((const float*)Xe_)[xi];
                }
                s0 += w * xv[0]; s1 += w * xv[1]; s2 += w * xv[2]; s3 += w * xv[3];
            }
            double sums[4] = {s0, s1, s2, s3};
            const double scale = bnd[cofs + o];
            const double be = (double)bnr[1 * O + o];
            const double mu = (double)bnr[2 * O + o];
            double bi = 0.0;
            if constexpr (OUT_MODE != 0) bi = (double)bias[o];
            double v = 0.0;
#pragma unroll
            for (int t = 0; t < TT; ++t) {
                const double val = (sums[t] + bi - mu) * scale + be;
                v = v + (val - v) * 0.5;
                const double sd = (v >= 1.0) ? 1.0 : 0.0;
                const size_t idx = (((size_t)t * BB + b) * O + o) * NN + n0 + nl;
                if constexpr (OUT_MODE == 0)
                    ((u16*)Out_)[idx] = (sd > 0.5) ? (u16)0x3F80 : (u16)0;
                else if constexpr (OUT_MODE == 1) {
                    float xn = (float)((double)base[idx] + sd);
                    ((float*)Out_)[idx] = xn;
                    const size_t a = ((size_t)t * BB + b) * NN + n0 + nl;
                    u16 hh = bf16_rne(xn);
                    OutH[a * CC + o] = hh;
                    OutL[a * CC + o] = bf16_rne(xn - bf16f(hh));
                } else if constexpr (OUT_MODE == 2) {
                    const size_t a = ((size_t)t * BB + b) * NN + n0 + nl;
                    ((u16*)Out_)[a * O + o] = (sd > 0.5) ? (u16)0x3F80 : (u16)0;
                } else ((float*)Out_)[idx] = (float)((double)base[idx] + sd);
                v = v * (1.0 - sd);
            }
        }
    }
}

// kv[t,b,h,d,e] = sum_n k[...]*v[...]; bf16 spike inputs (exact)
__global__ __launch_bounds__(256) void kv_kernel(
    const u16* __restrict__ k_s, const u16* __restrict__ v_s,
    float* __restrict__ kv)
{
    const int blk = blockIdx.x;
    const int h = blk & 7;
    const int m = blk >> 3;
    __shared__ float ks[32][65];
    __shared__ float vs[32][65];
    const int tid = threadIdx.x;
    const int d = tid >> 3;
    const int e0 = (tid & 7) * 4;
    float acc[4] = {0.f, 0.f, 0.f, 0.f};
    const size_t basek = ((size_t)m * CC + h * DD) * NN;
    for (int nc = 0; nc < NN; nc += 64) {
        for (int i = tid; i < 2048; i += 256) {
            int r = i >> 6, nl = i & 63;
            ks[r][nl] = bf16f(k_s[basek + (size_t)r * NN + nc + nl]);
            vs[r][nl] = bf16f(v_s[basek + (size_t)r * NN + nc + nl]);
        }
        __syncthreads();
        for (int nl = 0; nl < 64; ++nl) {
            float kd = ks[d][nl];
#pragma unroll
            for (int j = 0; j < 4; ++j) acc[j] += kd * vs[e0 + j][nl];
        }
        __syncthreads();
    }
#pragma unroll
    for (int j = 0; j < 4; ++j)
        kv[(size_t)blk * 1024 + d * 32 + e0 + j] = acc[j];
}

// a = 0.125 * q @ kv -> LIF(0.5); bf16 q spikes (exact); bf16 spike out [c][n]
__global__ __launch_bounds__(256) void attn_a_lif(
    const u16* __restrict__ q_s, const float* __restrict__ kv,
    u16* __restrict__ a_s)
{
    const int tid = threadIdx.x;
    const int n = blockIdx.x * 256 + tid;
    const int c = blockIdx.y;
    const int b = blockIdx.z;
    const int h = c >> 5;
    const int e = c & 31;
    __shared__ float kvs[TT][32];
    if (tid < 128) {
        int t = tid >> 5, d2 = tid & 31;
        kvs[t][d2] = kv[(((size_t)t * BB + b) * HEADS + h) * 1024 + d2 * 32 + e];
    }
    __syncthreads();
    float val[TT];
#pragma unroll
    for (int t = 0; t < TT; ++t) {
        float s = 0.f;
        const size_t qb = (((size_t)t * BB + b) * CC + h * DD) * NN + n;
#pragma unroll 8
        for (int d2 = 0; d2 < 32; ++d2)
            s += bf16f(q_s[qb + (size_t)d2 * NN]) * kvs[t][d2];
        val[t] = s * 0.125f;
    }
    float v = 0.f;
#pragma unroll
    for (int t = 0; t < TT; ++t) {
        v = v + (val[t] - v) * 0.5f;
        float s = (v >= 0.5f) ? 1.f : 0.f;
        a_s[(((size_t)t * BB + b) * CC + c) * NN + n] = (s > 0.5f) ? (u16)0x3F80 : (u16)0;
        v = v * (1.f - s);
    }
}

extern "C" void kernel_launch(void* const* d_in, const int* in_sizes, int n_in,
                              void* d_out, int out_size, void* d_ws, size_t ws_size,
                              hipStream_t stream)
{
    const float* x       = (const float*)d_in[0];
    const float* q_w     = (const float*)d_in[1];
    const float* q_bn    = (const float*)d_in[2];
    const float* k_w     = (const float*)d_in[3];
    const float* k_bn    = (const float*)d_in[4];
    const float* v_w     = (const float*)d_in[5];
    const float* v_bn    = (const float*)d_in[6];
    const float* proj_w  = (const float*)d_in[7];
    const float* proj_b  = (const float*)d_in[8];
    const float* proj_bn = (const float*)d_in[9];
    const float* mlp1_w  = (const float*)d_in[10];
    const float* mlp1_b  = (const float*)d_in[11];
    const float* mlp1_bn = (const float*)d_in[12];
    const float* mlp2_w  = (const float*)d_in[13];
    const float* mlp2_b  = (const float*)d_in[14];
    const float* mlp2_bn = (const float*)d_in[15];

    const size_t SZ = (size_t)TT * BB * CC * NN;   // 8388608
    char* ws = (char*)d_ws;
    // timeline-overlaid layout (bytes, in units of SZ*2 = 16.75 MB):
    u16*   q_s  = (u16*)(ws);                 // [0,2SZ)   dead after attn
    u16*   k_s  = (u16*)(ws + SZ * 2);        // [2,4)SZ   dead after kv
    u16*   v_s  = (u16*)(ws + SZ * 4);        // [4,6)SZ   dead after kv
    u16*   xTh  = (u16*)(ws + SZ * 6);        // [6,8)SZ   dead after qkv
    u16*   xTl  = (u16*)(ws + SZ * 8);        // [8,10)SZ  dead after qkv
    u16*   a_s  = (u16*)(ws + SZ * 6);        // overlays xTh (written by attn)
    u16*   aT   = (u16*)(ws + SZ * 8);        // overlays xTl (transpose of a_s)
    float* x_new= (float*)(ws);               // [0,4)SZ   overlays q_s+k_s
    u16*   h1T  = (u16*)(ws + SZ * 4);        // [4,12)SZ  overlays v_s,a_s,aT (after proj)
    u16*   xnTh = (u16*)(ws + SZ * 12);       // [12,14)SZ
    u16*   xnTl = (u16*)(ws + SZ * 14);       // [14,16)SZ
    char* wp = ws + SZ * 16;
    float* kvb = (float*)wp; wp += (size_t)262144 * 4;
    u16* qh  = (u16*)wp; wp += 65536 * 2;  u16* ql  = (u16*)wp; wp += 65536 * 2;
    u16* kh  = (u16*)wp; wp += 65536 * 2;  u16* kl  = (u16*)wp; wp += 65536 * 2;
    u16* vh  = (u16*)wp; wp += 65536 * 2;  u16* vl  = (u16*)wp; wp += 65536 * 2;
    u16* ph  = (u16*)wp; wp += 65536 * 2;  u16* pl  = (u16*)wp; wp += 65536 * 2;
    u16* m1h = (u16*)wp; wp += 262144 * 2; u16* m1l = (u16*)wp; wp += 262144 * 2;
    u16* m2h = (u16*)wp; wp += 262144 * 2; u16* m2l = (u16*)wp; wp += 262144 * 2;
    float2* bnf = (float2*)wp; wp += 2304 * 8;
    double* bnd = (double*)wp;

    dim3 blk(256);

    // prep: weight splits (k-contiguous), x transpose+split, BN constants
    prep_split<<<dim3(64),  blk, 0, stream>>>(q_w,    qh,  ql,  65536 / 4);
    prep_split<<<dim3(64),  blk, 0, stream>>>(k_w,    kh,  kl,  65536 / 4);
    prep_split<<<dim3(64),  blk, 0, stream>>>(v_w,    vh,  vl,  65536 / 4);
    prep_split<<<dim3(64),  blk, 0, stream>>>(proj_w, ph,  pl,  65536 / 4);
    prep_split<<<dim3(256), blk, 0, stream>>>(mlp1_w, m1h, m1l, 262144 / 4);
    prep_split<<<dim3(256), blk, 0, stream>>>(mlp2_w, m2h, m2l, 262144 / 4);
    trans_split<256, 1024><<<dim3(16, 4, 32), blk, 0, stream>>>(x, xTh, xTl);
    prep_bn<<<dim3(9), blk, 0, stream>>>(q_bn, k_bn, v_bn, proj_bn, mlp1_bn,
                                         mlp2_bn, proj_b, mlp1_b, mlp2_b, bnf, bnd);

    // qkv: xT(split) -> bf16 spike trains [c][n]
    conv_kernel<true, 256, 0, true, false, false, 256>
        <<<dim3(16, 12, 8), blk, 0, stream>>>(
        xTh, xTl, x, qh, ql, kh, kl, vh, vl, q_w, k_w, v_w,
        q_bn, k_bn, v_bn, nullptr, bnf, bnd,
        q_s, k_s, v_s, nullptr, nullptr, nullptr);

    // attention (exact)
    kv_kernel<<<dim3(TT * BB * HEADS), blk, 0, stream>>>(k_s, v_s, kvb);
    attn_a_lif<<<dim3(4, 256, 8), blk, 0, stream>>>(q_s, kvb, a_s);
    trans_u16<256, 1024><<<dim3(16, 4, 32), blk, 0, stream>>>(a_s, aT);

    // proj: aT (exact bf16 B) -> x_new f32 [c][n] + xnT hi/lo [n][c]
    conv_kernel<false, 256, 1, false, true, false, 256>
        <<<dim3(16, 4, 8), blk, 0, stream>>>(
        aT, nullptr, a_s, ph, pl, nullptr, nullptr, nullptr, nullptr,
        proj_w, nullptr, nullptr, proj_bn, nullptr, nullptr, proj_b,
        bnf + 768, bnd + 768, x_new, nullptr, nullptr, xnTh, xnTl, x);

    // mlp1: xnT(split) -> h1T bf16 spikes [n][o]
    conv_kernel<true, 256, 2, false, false, false, 1024>
        <<<dim3(16, 16, 8), blk, 0, stream>>>(
        xnTh, xnTl, x_new, m1h, m1l, nullptr, nullptr, nullptr, nullptr,
        mlp1_w, nullptr, nullptr, mlp1_bn, nullptr, nullptr, mlp1_b,
        bnf + 1024, bnd + 1024, h1T, nullptr, nullptr, nullptr, nullptr, nullptr);

    // mlp2: h1T (exact bf16 B, transposed recompute) -> d_out (+x_new)
    conv_kernel<false, 1024, 3, false, true, true, 256>
        <<<dim3(16, 4, 8), blk, 0, stream>>>(
        h1T, nullptr, h1T, m2h, m2l, nullptr, nullptr, nullptr, nullptr,
        mlp2_w, nullptr, nullptr, mlp2_bn, nullptr, nullptr, mlp2_b,
        bnf + 2048, bnd + 2048, d_out, nullptr, nullptr, nullptr, nullptr, x_new);
}